// Round 1
// baseline (1574.135 us; speedup 1.0000x reference)
//
#include <hip/hip_runtime.h>
#include <math.h>

// Problem constants (from reference): N=20000, E=320000, C=64, NS=4, NB=8, NH=64
#define PI_F        3.14159265358979323846f
#define SQRT2_F     1.41421356237309515f
#define SQRT3_F     1.73205080756887729f
#define INV_SQRT3_F 0.57735026918962576f
#define INV_AVG     0.25f   // 1/sqrt(16)

__device__ __forceinline__ float swish_f(float x) {
    return x / (1.f + __expf(-x));
}

// ---------------------------------------------------------------------------
// K1: per-node up-projection  s = ns@Wus, v[:, :, m] = nv[:,:,m]@Wuv
//     Also zero-initializes the aggregation buffers (ws is poisoned 0xAA).
//     wave-per-node, lane = output channel o. Weights (32KB) stay L1-hot.
// ---------------------------------------------------------------------------
__global__ __launch_bounds__(256) void k_node_up(
    const float* __restrict__ ns, const float* __restrict__ nv,
    const float* __restrict__ Wus, const float* __restrict__ Wuv,
    float* __restrict__ s_up, float* __restrict__ v_up,
    float* __restrict__ agg_s, float* __restrict__ agg_v)
{
    const int lane = threadIdx.x & 63;
    const int wq   = __builtin_amdgcn_readfirstlane(threadIdx.x >> 6);
    const int n    = blockIdx.x * 4 + wq;

    const float* nsr = ns + n * 64;
    const float* nvr = nv + n * 192;
    float acc = 0.f, a0 = 0.f, a1 = 0.f, a2 = 0.f;
    for (int i = 0; i < 64; ++i) {
        const float s = nsr[i];                 // uniform -> scalar load
        acc = fmaf(s, Wus[i*64 + lane], acc);   // coalesced, L1-hot
        const float wv = Wuv[i*64 + lane];
        a0 = fmaf(nvr[i*3+0], wv, a0);
        a1 = fmaf(nvr[i*3+1], wv, a1);
        a2 = fmaf(nvr[i*3+2], wv, a2);
    }
    s_up[n*64 + lane] = acc;
    v_up[(n*64 + lane)*3 + 0] = a0;
    v_up[(n*64 + lane)*3 + 1] = a1;
    v_up[(n*64 + lane)*3 + 2] = a2;

    agg_s[n*128 + lane]      = 0.f;
    agg_s[n*128 + 64 + lane] = 0.f;
    #pragma unroll
    for (int k = 0; k < 6; ++k) agg_v[n*384 + k*64 + lane] = 0.f;
}

// ---------------------------------------------------------------------------
// K2: edge kernel. Block = 256 threads = 4 waves, 64 edges per block.
//  A1: bessel features + MLP layer0 -> h1 tile (LDS, stride 68)
//  A2: layer1 -> h2 tile (LDS, stride 65), W1 reused 16x per read
//  B : mix = h2 @ W_mlp2 as a 64x256 per-block GEMM. Wave w owns output
//      cols [64w,64w+64), lane = local edge. W2 addresses are wave-uniform
//      -> scalar-cache loads; h2 is one broadcast-free ds_read per i.
//      Result transposed into a swizzled 64KB LDS tile (conflict-free both ways).
//  C : messages * mix, scatter with native f32 atomics (coalesced per row).
//  LDS = exactly 64KB -> 2 blocks/CU.
// ---------------------------------------------------------------------------
__global__ __launch_bounds__(256, 2) void k_edge(
    const float* __restrict__ vecs,
    const int*   __restrict__ snd_idx, const int* __restrict__ rcv_idx,
    const float* __restrict__ W0, const float* __restrict__ W1,
    const float* __restrict__ W2,
    const float* __restrict__ s_up, const float* __restrict__ v_up,
    float* __restrict__ agg_s, float* __restrict__ agg_v)
{
    __shared__ float lds[16384];               // 64 KB, phase-overlaid
    const int lane = threadIdx.x & 63;
    const int wq   = __builtin_amdgcn_readfirstlane(threadIdx.x >> 6);
    const int e0   = blockIdx.x * 64;

    // ---- A1: bessel + layer0. h1t[j][e] at lds[j*68 + e_loc] ----
    for (int t = 0; t < 16; ++t) {
        const int le = wq*16 + t;
        const int e  = e0 + le;
        const float vx = vecs[e*3+0], vy = vecs[e*3+1], vz = vecs[e*3+2];
        const float x  = sqrtf(vx*vx + vy*vy + vz*vz);
        const float sx = (x == 0.f) ? 1.f : x;
        float s1, c1;
        __sincosf(PI_F * x, &s1, &c1);
        const float u  = fminf(x, 1.f);
        const float u2 = u*u, u3 = u2*u;
        const float u6 = u3*u3, u7 = u6*u, u8 = u6*u2;
        const float env  = (x < 1.f) ? (1.f - 28.f*u6 + 48.f*u7 - 21.f*u8) : 0.f;
        const float pref = SQRT2_F * env / sx;
        // sin(n*pi*x) via Chebyshev recurrence: s_{n+1} = 2cos(pi x) s_n - s_{n-1}
        float h1 = 0.f;
        float sn = s1, snm1 = 0.f;
        const float twoc = 2.f * c1;
        #pragma unroll
        for (int b = 0; b < 8; ++b) {
            h1 = fmaf(pref * sn, W0[b*64 + lane], h1);
            const float snext = fmaf(twoc, sn, -snm1);
            snm1 = sn; sn = snext;
        }
        lds[lane*68 + le] = swish_f(h1);
    }
    __syncthreads();

    // ---- A2: layer1. h2t[j][e] at lds[4352 + j*65 + e_loc] ----
    {
        const int eb = wq * 16;
        float acc2[16];
        #pragma unroll
        for (int t = 0; t < 16; ++t) acc2[t] = 0.f;
        for (int i = 0; i < 64; ++i) {
            const float w1 = W1[i*64 + lane];        // coalesced, L1-hot
            const float4 q0 = *reinterpret_cast<const float4*>(&lds[i*68 + eb + 0]);
            const float4 q1 = *reinterpret_cast<const float4*>(&lds[i*68 + eb + 4]);
            const float4 q2 = *reinterpret_cast<const float4*>(&lds[i*68 + eb + 8]);
            const float4 q3 = *reinterpret_cast<const float4*>(&lds[i*68 + eb + 12]);
            acc2[0]  = fmaf(q0.x, w1, acc2[0]);
            acc2[1]  = fmaf(q0.y, w1, acc2[1]);
            acc2[2]  = fmaf(q0.z, w1, acc2[2]);
            acc2[3]  = fmaf(q0.w, w1, acc2[3]);
            acc2[4]  = fmaf(q1.x, w1, acc2[4]);
            acc2[5]  = fmaf(q1.y, w1, acc2[5]);
            acc2[6]  = fmaf(q1.z, w1, acc2[6]);
            acc2[7]  = fmaf(q1.w, w1, acc2[7]);
            acc2[8]  = fmaf(q2.x, w1, acc2[8]);
            acc2[9]  = fmaf(q2.y, w1, acc2[9]);
            acc2[10] = fmaf(q2.z, w1, acc2[10]);
            acc2[11] = fmaf(q2.w, w1, acc2[11]);
            acc2[12] = fmaf(q3.x, w1, acc2[12]);
            acc2[13] = fmaf(q3.y, w1, acc2[13]);
            acc2[14] = fmaf(q3.z, w1, acc2[14]);
            acc2[15] = fmaf(q3.w, w1, acc2[15]);
        }
        #pragma unroll
        for (int t = 0; t < 16; ++t)
            lds[4352 + lane*65 + eb + t] = swish_f(acc2[t]);
    }
    __syncthreads();

    // ---- B: mix GEMM. lane = local edge; wave covers cols [wo, wo+64) ----
    const int wo = wq * 64;
    float acc[64];
    #pragma unroll
    for (int j = 0; j < 64; ++j) acc[j] = 0.f;
    for (int i = 0; i < 64; ++i) {
        const float hv = lds[4352 + i*65 + lane];     // conflict-free ds_read
        const float* wr = W2 + i*256 + wo;            // wave-uniform -> s_load
        #pragma unroll
        for (int j = 0; j < 64; ++j) acc[j] = fmaf(hv, wr[j], acc[j]);
    }
    __syncthreads();   // all h2t reads done before mix overlay write
    // mixT[o][e] swizzled: addr = o*64 + ((e + o) & 63)  (conflict-free R & W)
    #pragma unroll
    for (int j = 0; j < 64; ++j) {
        const int o = wo + j;
        lds[o*64 + ((lane + o) & 63)] = acc[j];
    }
    __syncthreads();

    // ---- C: messages + scatter-add ----
    for (int t = 0; t < 16; ++t) {
        const int le = wq*16 + t;
        const int e  = e0 + le;
        const float vx = vecs[e*3+0], vy = vecs[e*3+1], vz = vecs[e*3+2];
        const float x  = sqrtf(vx*vx + vy*vy + vz*vz);
        const float sx = (x == 0.f) ? 1.f : x;
        const float ys = SQRT3_F / sx;
        const float Y0 = vx*ys, Y1 = vy*ys, Y2 = vz*ys;
        const float msk = (x == 0.f) ? 0.f : 1.f;   // ref: mix=0 where len==0
        const int snd = __builtin_amdgcn_readfirstlane(snd_idx[e]);
        const int rcv = __builtin_amdgcn_readfirstlane(rcv_idx[e]);

        const int o0 = lane, o1 = 64 + lane, o2 = 128 + lane, o3 = 192 + lane;
        const float mix0 = lds[o0*64 + ((le + o0) & 63)] * msk;
        const float mix1 = lds[o1*64 + ((le + o1) & 63)] * msk;
        const float mix2 = lds[o2*64 + ((le + o2) & 63)] * msk;
        const float mix3 = lds[o3*64 + ((le + o3) & 63)] * msk;

        const float msv = s_up[snd*64 + lane];              // coalesced gather
        const float mv0 = v_up[(snd*64 + lane)*3 + 0];
        const float mv1 = v_up[(snd*64 + lane)*3 + 1];
        const float mv2 = v_up[(snd*64 + lane)*3 + 2];
        const float tt0 = (mv0*Y0 + mv1*Y1 + mv2*Y2) * INV_SQRT3_F;

        float* as = agg_s + rcv*128;
        unsafeAtomicAdd(as + lane,      msv * mix0);
        unsafeAtomicAdd(as + 64 + lane, tt0 * mix1);
        float* av = agg_v + rcv*384;
        unsafeAtomicAdd(av + lane*3 + 0, mv0 * mix2);
        unsafeAtomicAdd(av + lane*3 + 1, mv1 * mix2);
        unsafeAtomicAdd(av + lane*3 + 2, mv2 * mix2);
        unsafeAtomicAdd(av + 192 + lane*3 + 0, msv * Y0 * mix3);
        unsafeAtomicAdd(av + 192 + lane*3 + 1, msv * Y1 * mix3);
        unsafeAtomicAdd(av + 192 + lane*3 + 2, msv * Y2 * mix3);
    }
}

// ---------------------------------------------------------------------------
// K3: node down-projection + specie skip + swish gating -> output (N,256)
//     wave-per-node, lane = output channel. agg rows are wave-uniform
//     (scalar loads); weights stream from L2 (~144KB/node — round-2 target).
// ---------------------------------------------------------------------------
__global__ __launch_bounds__(256) void k_node_down(
    const float* __restrict__ ns, const float* __restrict__ nv,
    const int*   __restrict__ spec_idx,
    const float* __restrict__ Wds, const float* __restrict__ Wdv,
    const float* __restrict__ Wsks, const float* __restrict__ Wskv,
    const float* __restrict__ agg_s, const float* __restrict__ agg_v,
    float* __restrict__ out)
{
    const int lane = threadIdx.x & 63;
    const int wq   = __builtin_amdgcn_readfirstlane(threadIdx.x >> 6);
    const int n    = blockIdx.x * 4 + wq;
    const int spec = __builtin_amdgcn_readfirstlane(spec_idx[n]);

    const float* ar  = agg_s + n*128;
    const float* avr = agg_v + n*384;
    float s0 = 0.f, s1 = 0.f, v0 = 0.f, v1 = 0.f, v2 = 0.f;
    for (int i = 0; i < 128; ++i) {
        const float a = ar[i] * INV_AVG;
        s0 = fmaf(a, Wds[i*128 + lane], s0);
        s1 = fmaf(a, Wds[i*128 + 64 + lane], s1);
        const float wv = Wdv[i*64 + lane];
        v0 = fmaf(avr[i*3+0] * INV_AVG, wv, v0);
        v1 = fmaf(avr[i*3+1] * INV_AVG, wv, v1);
        v2 = fmaf(avr[i*3+2] * INV_AVG, wv, v2);
    }
    const float* nsr = ns + n*64;
    const float* nvr = nv + n*192;
    const float* Ws  = Wsks + spec*8192;   // (64,128)
    const float* Wv  = Wskv + spec*4096;   // (64,64)
    for (int i = 0; i < 64; ++i) {
        const float s = nsr[i];
        s0 = fmaf(s, Ws[i*128 + lane], s0);
        s1 = fmaf(s, Ws[i*128 + 64 + lane], s1);
        const float wv = Wv[i*64 + lane];
        v0 = fmaf(nvr[i*3+0], wv, v0);
        v1 = fmaf(nvr[i*3+1], wv, v1);
        v2 = fmaf(nvr[i*3+2], wv, v2);
    }
    const float scal = swish_f(s0);
    const float gate = swish_f(s1);
    out[n*256 + lane]               = scal;
    out[n*256 + 64 + lane*3 + 0]    = v0 * gate;
    out[n*256 + 64 + lane*3 + 1]    = v1 * gate;
    out[n*256 + 64 + lane*3 + 2]    = v2 * gate;
}

// ---------------------------------------------------------------------------
extern "C" void kernel_launch(void* const* d_in, const int* in_sizes, int n_in,
                              void* d_out, int out_size, void* d_ws, size_t ws_size,
                              hipStream_t stream)
{
    (void)in_sizes; (void)n_in; (void)out_size; (void)ws_size;

    const float* vectors      = (const float*)d_in[0];
    const float* node_scalars = (const float*)d_in[1];
    const float* node_vectors = (const float*)d_in[2];
    const int*   node_specie  = (const int*)d_in[3];
    const int*   senders      = (const int*)d_in[4];
    const int*   receivers    = (const int*)d_in[5];
    const float* W_skip_s     = (const float*)d_in[6];
    const float* W_skip_v     = (const float*)d_in[7];
    const float* W_up_s       = (const float*)d_in[8];
    const float* W_up_v       = (const float*)d_in[9];
    const float* W_mlp0       = (const float*)d_in[10];
    const float* W_mlp1       = (const float*)d_in[11];
    const float* W_mlp2       = (const float*)d_in[12];
    const float* W_down_s     = (const float*)d_in[13];
    const float* W_down_v     = (const float*)d_in[14];
    float* out = (float*)d_out;

    // workspace layout (floats): total 15,360,000 f32 = 61.44 MB
    float* ws    = (float*)d_ws;
    float* s_up  = ws;                  // N*64        = 1,280,000
    float* v_up  = s_up + 1280000;      // N*64*3      = 3,840,000
    float* agg_s = v_up + 3840000;      // N*128       = 2,560,000
    float* agg_v = agg_s + 2560000;     // N*128*3     = 7,680,000

    hipLaunchKernelGGL(k_node_up, dim3(5000), dim3(256), 0, stream,
        node_scalars, node_vectors, W_up_s, W_up_v, s_up, v_up, agg_s, agg_v);
    hipLaunchKernelGGL(k_edge, dim3(5000), dim3(256), 0, stream,
        vectors, senders, receivers, W_mlp0, W_mlp1, W_mlp2,
        s_up, v_up, agg_s, agg_v);
    hipLaunchKernelGGL(k_node_down, dim3(5000), dim3(256), 0, stream,
        node_scalars, node_vectors, node_specie, W_down_s, W_down_v,
        W_skip_s, W_skip_v, agg_s, agg_v, out);
}

// Round 2
// 772.073 us; speedup vs baseline: 2.0388x; 2.0388x over previous
//
#include <hip/hip_runtime.h>
#include <math.h>

// Problem constants (from reference): N=20000, E=320000, C=64, NS=4, NB=8, NH=64
#define PI_F        3.14159265358979323846f
#define SQRT2_F     1.41421356237309515f
#define SQRT3_F     1.73205080756887729f
#define INV_SQRT3_F 0.57735026918962576f
#define INV_AVG     0.25f   // 1/sqrt(16)

#define N_NODES 20000
#define N_EDGES 320000

__device__ __forceinline__ float swish_f(float x) {
    return x / (1.f + __expf(-x));
}

// ---------------------------------------------------------------------------
// Sort pipeline: counting sort of edge IDs by receiver so the edge kernel can
// accumulate per-receiver in registers and flush atomics only on segment
// boundaries (~8x fewer atomics; atomics were ~86% of round-1 k_edge time).
// ---------------------------------------------------------------------------
__global__ __launch_bounds__(256) void k_zero_cnt(int* __restrict__ cnt) {
    const int i = blockIdx.x * 256 + threadIdx.x;
    if (i < N_NODES) cnt[i] = 0;
}

__global__ __launch_bounds__(256) void k_hist(const int* __restrict__ rcv,
                                              int* __restrict__ cnt) {
    const int e = blockIdx.x * 256 + threadIdx.x;
    if (e < N_EDGES) atomicAdd(&cnt[rcv[e]], 1);
}

// single block, 1024 threads, 20 bins/thread (1024*20 >= 20000)
__global__ __launch_bounds__(1024) void k_scan(const int* __restrict__ cnt,
                                               int* __restrict__ cursor) {
    __shared__ int part[1024];
    const int t = threadIdx.x;
    const int base = t * 20;
    int s = 0;
    #pragma unroll
    for (int j = 0; j < 20; ++j) {
        const int idx = base + j;
        if (idx < N_NODES) s += cnt[idx];
    }
    part[t] = s;
    __syncthreads();
    for (int d = 1; d < 1024; d <<= 1) {          // Hillis-Steele inclusive
        const int v = (t >= d) ? part[t - d] : 0;
        __syncthreads();
        part[t] += v;
        __syncthreads();
    }
    int run = (t == 0) ? 0 : part[t - 1];          // exclusive base
    for (int j = 0; j < 20; ++j) {
        const int idx = base + j;
        if (idx < N_NODES) { cursor[idx] = run; run += cnt[idx]; }
    }
}

__global__ __launch_bounds__(256) void k_scatter(const int* __restrict__ rcv,
                                                 int* __restrict__ cursor,
                                                 int* __restrict__ perm) {
    const int e = blockIdx.x * 256 + threadIdx.x;
    if (e < N_EDGES) {
        const int pos = atomicAdd(&cursor[rcv[e]], 1);
        perm[pos] = e;
    }
}

// ---------------------------------------------------------------------------
// K1: per-node up-projection  s = ns@Wus, v[:, :, m] = nv[:,:,m]@Wuv
//     Also zero-initializes the aggregation buffers (ws is poisoned 0xAA).
//     wave-per-node, lane = output channel o. Weights (32KB) stay L1-hot.
// ---------------------------------------------------------------------------
__global__ __launch_bounds__(256) void k_node_up(
    const float* __restrict__ ns, const float* __restrict__ nv,
    const float* __restrict__ Wus, const float* __restrict__ Wuv,
    float* __restrict__ s_up, float* __restrict__ v_up,
    float* __restrict__ agg_s, float* __restrict__ agg_v)
{
    const int lane = threadIdx.x & 63;
    const int wq   = __builtin_amdgcn_readfirstlane(threadIdx.x >> 6);
    const int n    = blockIdx.x * 4 + wq;

    const float* nsr = ns + n * 64;
    const float* nvr = nv + n * 192;
    float acc = 0.f, a0 = 0.f, a1 = 0.f, a2 = 0.f;
    for (int i = 0; i < 64; ++i) {
        const float s = nsr[i];                 // uniform -> scalar load
        acc = fmaf(s, Wus[i*64 + lane], acc);   // coalesced, L1-hot
        const float wv = Wuv[i*64 + lane];
        a0 = fmaf(nvr[i*3+0], wv, a0);
        a1 = fmaf(nvr[i*3+1], wv, a1);
        a2 = fmaf(nvr[i*3+2], wv, a2);
    }
    s_up[n*64 + lane] = acc;
    v_up[(n*64 + lane)*3 + 0] = a0;
    v_up[(n*64 + lane)*3 + 1] = a1;
    v_up[(n*64 + lane)*3 + 2] = a2;

    agg_s[n*128 + lane]      = 0.f;
    agg_s[n*128 + 64 + lane] = 0.f;
    #pragma unroll
    for (int k = 0; k < 6; ++k) agg_v[n*384 + k*64 + lane] = 0.f;
}

// ---------------------------------------------------------------------------
// K2: edge kernel over RECEIVER-SORTED edge IDs (perm). Block = 4 waves,
//     64 edges. Phases A1/A2/B as round 1 (h1 tile stride 68, h2 stride 65,
//     mix GEMM with wave-uniform W2 scalar loads, swizzled 64KB mix tile).
//     Phase C: per-wave register accumulation over the sorted edge run,
//     atomic flush only when the receiver changes (~2 flushes / 16 edges).
// ---------------------------------------------------------------------------
__global__ __launch_bounds__(256, 2) void k_edge(
    const float* __restrict__ vecs,
    const int*   __restrict__ snd_idx, const int* __restrict__ rcv_idx,
    const int*   __restrict__ perm,
    const float* __restrict__ W0, const float* __restrict__ W1,
    const float* __restrict__ W2,
    const float* __restrict__ s_up, const float* __restrict__ v_up,
    float* __restrict__ agg_s, float* __restrict__ agg_v)
{
    __shared__ float lds[16384];               // 64 KB, phase-overlaid
    const int lane = threadIdx.x & 63;
    const int wq   = __builtin_amdgcn_readfirstlane(threadIdx.x >> 6);
    const int e0   = blockIdx.x * 64;

    // ---- A1: bessel + layer0. h1t[j][e] at lds[j*68 + e_loc] ----
    for (int t = 0; t < 16; ++t) {
        const int le = wq*16 + t;
        const int pe = __builtin_amdgcn_readfirstlane(perm[e0 + le]);
        const float vx = vecs[pe*3+0], vy = vecs[pe*3+1], vz = vecs[pe*3+2];
        const float x  = sqrtf(vx*vx + vy*vy + vz*vz);
        const float sx = (x == 0.f) ? 1.f : x;
        float s1, c1;
        __sincosf(PI_F * x, &s1, &c1);
        const float u  = fminf(x, 1.f);
        const float u2 = u*u, u3 = u2*u;
        const float u6 = u3*u3, u7 = u6*u, u8 = u6*u2;
        const float env  = (x < 1.f) ? (1.f - 28.f*u6 + 48.f*u7 - 21.f*u8) : 0.f;
        const float pref = SQRT2_F * env / sx;
        // sin(n*pi*x) via Chebyshev recurrence: s_{n+1} = 2cos(pi x) s_n - s_{n-1}
        float h1 = 0.f;
        float sn = s1, snm1 = 0.f;
        const float twoc = 2.f * c1;
        #pragma unroll
        for (int b = 0; b < 8; ++b) {
            h1 = fmaf(pref * sn, W0[b*64 + lane], h1);
            const float snext = fmaf(twoc, sn, -snm1);
            snm1 = sn; sn = snext;
        }
        lds[lane*68 + le] = swish_f(h1);
    }
    __syncthreads();

    // ---- A2: layer1. h2t[j][e] at lds[4352 + j*65 + e_loc] ----
    {
        const int eb = wq * 16;
        float acc2[16];
        #pragma unroll
        for (int t = 0; t < 16; ++t) acc2[t] = 0.f;
        for (int i = 0; i < 64; ++i) {
            const float w1 = W1[i*64 + lane];        // coalesced, L1-hot
            const float4 q0 = *reinterpret_cast<const float4*>(&lds[i*68 + eb + 0]);
            const float4 q1 = *reinterpret_cast<const float4*>(&lds[i*68 + eb + 4]);
            const float4 q2 = *reinterpret_cast<const float4*>(&lds[i*68 + eb + 8]);
            const float4 q3 = *reinterpret_cast<const float4*>(&lds[i*68 + eb + 12]);
            acc2[0]  = fmaf(q0.x, w1, acc2[0]);
            acc2[1]  = fmaf(q0.y, w1, acc2[1]);
            acc2[2]  = fmaf(q0.z, w1, acc2[2]);
            acc2[3]  = fmaf(q0.w, w1, acc2[3]);
            acc2[4]  = fmaf(q1.x, w1, acc2[4]);
            acc2[5]  = fmaf(q1.y, w1, acc2[5]);
            acc2[6]  = fmaf(q1.z, w1, acc2[6]);
            acc2[7]  = fmaf(q1.w, w1, acc2[7]);
            acc2[8]  = fmaf(q2.x, w1, acc2[8]);
            acc2[9]  = fmaf(q2.y, w1, acc2[9]);
            acc2[10] = fmaf(q2.z, w1, acc2[10]);
            acc2[11] = fmaf(q2.w, w1, acc2[11]);
            acc2[12] = fmaf(q3.x, w1, acc2[12]);
            acc2[13] = fmaf(q3.y, w1, acc2[13]);
            acc2[14] = fmaf(q3.z, w1, acc2[14]);
            acc2[15] = fmaf(q3.w, w1, acc2[15]);
        }
        #pragma unroll
        for (int t = 0; t < 16; ++t)
            lds[4352 + lane*65 + eb + t] = swish_f(acc2[t]);
    }
    __syncthreads();

    // ---- B: mix GEMM. lane = local edge; wave covers cols [wo, wo+64) ----
    const int wo = wq * 64;
    {
        float acc[64];
        #pragma unroll
        for (int j = 0; j < 64; ++j) acc[j] = 0.f;
        for (int i = 0; i < 64; ++i) {
            const float hv = lds[4352 + i*65 + lane];     // conflict-free ds_read
            const float* wr = W2 + i*256 + wo;            // wave-uniform -> s_load
            #pragma unroll
            for (int j = 0; j < 64; ++j) acc[j] = fmaf(hv, wr[j], acc[j]);
        }
        __syncthreads();   // all h2t reads done before mix overlay write
        // mixT[o][e] swizzled: addr = o*64 + ((e + o) & 63)  (conflict-free R & W)
        #pragma unroll
        for (int j = 0; j < 64; ++j) {
            const int o = wo + j;
            lds[o*64 + ((lane + o) & 63)] = acc[j];
        }
    }
    __syncthreads();

    // ---- C: messages + segmented scatter-add (sorted by receiver) ----
    int cur = -1;
    float r0 = 0.f, r1 = 0.f, r2 = 0.f, r3 = 0.f,
          r4 = 0.f, r5 = 0.f, r6 = 0.f, r7 = 0.f;

#define FLUSH_ACC() do {                                          \
        float* as_ = agg_s + cur*128;                             \
        unsafeAtomicAdd(as_ + lane,      r0);                     \
        unsafeAtomicAdd(as_ + 64 + lane, r1);                     \
        float* av_ = agg_v + cur*384;                             \
        unsafeAtomicAdd(av_ + lane*3 + 0, r2);                    \
        unsafeAtomicAdd(av_ + lane*3 + 1, r3);                    \
        unsafeAtomicAdd(av_ + lane*3 + 2, r4);                    \
        unsafeAtomicAdd(av_ + 192 + lane*3 + 0, r5);              \
        unsafeAtomicAdd(av_ + 192 + lane*3 + 1, r6);              \
        unsafeAtomicAdd(av_ + 192 + lane*3 + 2, r7);              \
    } while (0)

    for (int t = 0; t < 16; ++t) {
        const int le  = wq*16 + t;
        const int pe  = __builtin_amdgcn_readfirstlane(perm[e0 + le]);
        const int rcv = __builtin_amdgcn_readfirstlane(rcv_idx[pe]);
        const int snd = __builtin_amdgcn_readfirstlane(snd_idx[pe]);

        if (rcv != cur) {                      // wave-uniform branch
            if (cur >= 0) FLUSH_ACC();
            r0 = r1 = r2 = r3 = r4 = r5 = r6 = r7 = 0.f;
            cur = rcv;
        }

        const float vx = vecs[pe*3+0], vy = vecs[pe*3+1], vz = vecs[pe*3+2];
        const float x  = sqrtf(vx*vx + vy*vy + vz*vz);
        const float sx = (x == 0.f) ? 1.f : x;
        const float ys = SQRT3_F / sx;
        const float Y0 = vx*ys, Y1 = vy*ys, Y2 = vz*ys;
        const float msk = (x == 0.f) ? 0.f : 1.f;   // ref: mix=0 where len==0

        const int o0 = lane, o1 = 64 + lane, o2 = 128 + lane, o3 = 192 + lane;
        const float mix0 = lds[o0*64 + ((le + o0) & 63)] * msk;
        const float mix1 = lds[o1*64 + ((le + o1) & 63)] * msk;
        const float mix2 = lds[o2*64 + ((le + o2) & 63)] * msk;
        const float mix3 = lds[o3*64 + ((le + o3) & 63)] * msk;

        const float msv = s_up[snd*64 + lane];              // coalesced gather
        const float mv0 = v_up[(snd*64 + lane)*3 + 0];
        const float mv1 = v_up[(snd*64 + lane)*3 + 1];
        const float mv2 = v_up[(snd*64 + lane)*3 + 2];
        const float tt0 = (mv0*Y0 + mv1*Y1 + mv2*Y2) * INV_SQRT3_F;

        r0 = fmaf(msv, mix0, r0);
        r1 = fmaf(tt0, mix1, r1);
        r2 = fmaf(mv0, mix2, r2);
        r3 = fmaf(mv1, mix2, r3);
        r4 = fmaf(mv2, mix2, r4);
        r5 = fmaf(msv * Y0, mix3, r5);
        r6 = fmaf(msv * Y1, mix3, r6);
        r7 = fmaf(msv * Y2, mix3, r7);
    }
    FLUSH_ACC();
#undef FLUSH_ACC
}

// ---------------------------------------------------------------------------
// K3: node down-projection + specie skip + swish gating -> output (N,256)
//     wave-per-node, lane = output channel. agg rows are wave-uniform
//     (scalar loads); weights stream from L2 (~144KB/node — next target).
// ---------------------------------------------------------------------------
__global__ __launch_bounds__(256) void k_node_down(
    const float* __restrict__ ns, const float* __restrict__ nv,
    const int*   __restrict__ spec_idx,
    const float* __restrict__ Wds, const float* __restrict__ Wdv,
    const float* __restrict__ Wsks, const float* __restrict__ Wskv,
    const float* __restrict__ agg_s, const float* __restrict__ agg_v,
    float* __restrict__ out)
{
    const int lane = threadIdx.x & 63;
    const int wq   = __builtin_amdgcn_readfirstlane(threadIdx.x >> 6);
    const int n    = blockIdx.x * 4 + wq;
    const int spec = __builtin_amdgcn_readfirstlane(spec_idx[n]);

    const float* ar  = agg_s + n*128;
    const float* avr = agg_v + n*384;
    float s0 = 0.f, s1 = 0.f, v0 = 0.f, v1 = 0.f, v2 = 0.f;
    for (int i = 0; i < 128; ++i) {
        const float a = ar[i] * INV_AVG;
        s0 = fmaf(a, Wds[i*128 + lane], s0);
        s1 = fmaf(a, Wds[i*128 + 64 + lane], s1);
        const float wv = Wdv[i*64 + lane];
        v0 = fmaf(avr[i*3+0] * INV_AVG, wv, v0);
        v1 = fmaf(avr[i*3+1] * INV_AVG, wv, v1);
        v2 = fmaf(avr[i*3+2] * INV_AVG, wv, v2);
    }
    const float* nsr = ns + n*64;
    const float* nvr = nv + n*192;
    const float* Ws  = Wsks + spec*8192;   // (64,128)
    const float* Wv  = Wskv + spec*4096;   // (64,64)
    for (int i = 0; i < 64; ++i) {
        const float s = nsr[i];
        s0 = fmaf(s, Ws[i*128 + lane], s0);
        s1 = fmaf(s, Ws[i*128 + 64 + lane], s1);
        const float wv = Wv[i*64 + lane];
        v0 = fmaf(nvr[i*3+0], wv, v0);
        v1 = fmaf(nvr[i*3+1], wv, v1);
        v2 = fmaf(nvr[i*3+2], wv, v2);
    }
    const float scal = swish_f(s0);
    const float gate = swish_f(s1);
    out[n*256 + lane]               = scal;
    out[n*256 + 64 + lane*3 + 0]    = v0 * gate;
    out[n*256 + 64 + lane*3 + 1]    = v1 * gate;
    out[n*256 + 64 + lane*3 + 2]    = v2 * gate;
}

// ---------------------------------------------------------------------------
extern "C" void kernel_launch(void* const* d_in, const int* in_sizes, int n_in,
                              void* d_out, int out_size, void* d_ws, size_t ws_size,
                              hipStream_t stream)
{
    (void)in_sizes; (void)n_in; (void)out_size; (void)ws_size;

    const float* vectors      = (const float*)d_in[0];
    const float* node_scalars = (const float*)d_in[1];
    const float* node_vectors = (const float*)d_in[2];
    const int*   node_specie  = (const int*)d_in[3];
    const int*   senders      = (const int*)d_in[4];
    const int*   receivers    = (const int*)d_in[5];
    const float* W_skip_s     = (const float*)d_in[6];
    const float* W_skip_v     = (const float*)d_in[7];
    const float* W_up_s       = (const float*)d_in[8];
    const float* W_up_v       = (const float*)d_in[9];
    const float* W_mlp0       = (const float*)d_in[10];
    const float* W_mlp1       = (const float*)d_in[11];
    const float* W_mlp2       = (const float*)d_in[12];
    const float* W_down_s     = (const float*)d_in[13];
    const float* W_down_v     = (const float*)d_in[14];
    float* out = (float*)d_out;

    // workspace layout (floats): 15,360,000 f32 (61.44MB) + perm 320k ints.
    // cnt/cursor alias agg_s (dead before k_node_up re-zeroes agg_s).
    float* ws    = (float*)d_ws;
    float* s_up  = ws;                  // N*64        = 1,280,000
    float* v_up  = s_up + 1280000;      // N*64*3      = 3,840,000
    float* agg_s = v_up + 3840000;      // N*128       = 2,560,000
    float* agg_v = agg_s + 2560000;     // N*128*3     = 7,680,000
    int*   perm  = (int*)(agg_v + 7680000);  // E ints  = 320,000
    int*   cnt    = (int*)agg_s;        // aliased scratch (20,000 ints)
    int*   cursor = cnt + 20000;        // aliased scratch (20,000 ints)

    // counting sort of edge ids by receiver
    hipLaunchKernelGGL(k_zero_cnt, dim3(79),   dim3(256),  0, stream, cnt);
    hipLaunchKernelGGL(k_hist,     dim3(1250), dim3(256),  0, stream, receivers, cnt);
    hipLaunchKernelGGL(k_scan,     dim3(1),    dim3(1024), 0, stream, cnt, cursor);
    hipLaunchKernelGGL(k_scatter,  dim3(1250), dim3(256),  0, stream, receivers, cursor, perm);

    hipLaunchKernelGGL(k_node_up, dim3(5000), dim3(256), 0, stream,
        node_scalars, node_vectors, W_up_s, W_up_v, s_up, v_up, agg_s, agg_v);
    hipLaunchKernelGGL(k_edge, dim3(5000), dim3(256), 0, stream,
        vectors, senders, receivers, perm, W_mlp0, W_mlp1, W_mlp2,
        s_up, v_up, agg_s, agg_v);
    hipLaunchKernelGGL(k_node_down, dim3(5000), dim3(256), 0, stream,
        node_scalars, node_vectors, node_specie, W_down_s, W_down_v,
        W_skip_s, W_skip_v, agg_s, agg_v, out);
}

// Round 6
// 543.114 us; speedup vs baseline: 2.8983x; 1.4216x over previous
//
#include <hip/hip_runtime.h>
#include <math.h>

// Problem constants: N=20000, E=320000, C=64, NS=4, NB=8, NH=64
#define PI_F        3.14159265358979323846f
#define SQRT2_F     1.41421356237309515f
#define SQRT3_F     1.73205080756887729f
#define INV_SQRT3_F 0.57735026918962576f
#define INV_AVG     0.25f   // 1/sqrt(16)

#define N_NODES 20000
#define N_EDGES 320000

__device__ __forceinline__ float swish_f(float x) {
    return x / (1.f + __expf(-x));
}

// ---------------------------------------------------------------------------
// Edge counting sort by receiver (round-2, known good).
// ---------------------------------------------------------------------------
__global__ __launch_bounds__(256) void k_zero_cnt(int* __restrict__ cnt) {
    const int i = blockIdx.x * 256 + threadIdx.x;
    if (i < N_NODES) cnt[i] = 0;
}
__global__ __launch_bounds__(256) void k_hist(const int* __restrict__ rcv,
                                              int* __restrict__ cnt) {
    const int e = blockIdx.x * 256 + threadIdx.x;
    if (e < N_EDGES) atomicAdd(&cnt[rcv[e]], 1);
}
__global__ __launch_bounds__(1024) void k_scan(const int* __restrict__ cnt,
                                               int* __restrict__ cursor) {
    __shared__ int part[1024];
    const int t = threadIdx.x;
    const int base = t * 20;
    int s = 0;
    #pragma unroll
    for (int j = 0; j < 20; ++j) {
        const int idx = base + j;
        if (idx < N_NODES) s += cnt[idx];
    }
    part[t] = s;
    __syncthreads();
    for (int d = 1; d < 1024; d <<= 1) {
        const int v = (t >= d) ? part[t - d] : 0;
        __syncthreads();
        part[t] += v;
        __syncthreads();
    }
    int run = (t == 0) ? 0 : part[t - 1];
    for (int j = 0; j < 20; ++j) {
        const int idx = base + j;
        if (idx < N_NODES) { cursor[idx] = run; run += cnt[idx]; }
    }
}
__global__ __launch_bounds__(256) void k_scatter(const int* __restrict__ rcv,
                                                 int* __restrict__ cursor,
                                                 int* __restrict__ perm) {
    const int e = blockIdx.x * 256 + threadIdx.x;
    if (e < N_EDGES) {
        const int pos = atomicAdd(&cursor[rcv[e]], 1);
        perm[pos] = e;
    }
}

// ---------------------------------------------------------------------------
// K1: node up-projection + agg zero-init (round-2, known good).
// ---------------------------------------------------------------------------
__global__ __launch_bounds__(256) void k_node_up(
    const float* __restrict__ ns, const float* __restrict__ nv,
    const float* __restrict__ Wus, const float* __restrict__ Wuv,
    float* __restrict__ s_up, float* __restrict__ v_up,
    float* __restrict__ agg_s, float* __restrict__ agg_v)
{
    const int lane = threadIdx.x & 63;
    const int wq   = __builtin_amdgcn_readfirstlane(threadIdx.x >> 6);
    const int n    = blockIdx.x * 4 + wq;

    const float* nsr = ns + n * 64;
    const float* nvr = nv + n * 192;
    float acc = 0.f, a0 = 0.f, a1 = 0.f, a2 = 0.f;
    for (int i = 0; i < 64; ++i) {
        const float s = nsr[i];
        acc = fmaf(s, Wus[i*64 + lane], acc);
        const float wv = Wuv[i*64 + lane];
        a0 = fmaf(nvr[i*3+0], wv, a0);
        a1 = fmaf(nvr[i*3+1], wv, a1);
        a2 = fmaf(nvr[i*3+2], wv, a2);
    }
    s_up[n*64 + lane] = acc;
    v_up[(n*64 + lane)*3 + 0] = a0;
    v_up[(n*64 + lane)*3 + 1] = a1;
    v_up[(n*64 + lane)*3 + 2] = a2;

    agg_s[n*128 + lane]      = 0.f;
    agg_s[n*128 + 64 + lane] = 0.f;
    #pragma unroll
    for (int k = 0; k < 6; ++k) agg_v[n*384 + k*64 + lane] = 0.f;
}

// ---------------------------------------------------------------------------
// K2 v6 (BISECTION): v5 scaffolding with ALL-f32 VALU MLP (no MFMA, no fp16,
// no fragment packing, no row permutation). Isolates the register-direct
// segmented phase C + sort pipeline from the MFMA path.
//  h1v/h2v: [le][i] stride 69 (2-way bank aliasing only = free).
//  A1: bessel+W0 -> h1v rows of own wave.  A2: h1@W1 (reads only own rows ->
//  NO barrier after A1).  B: mixr[t][ntl] computed directly in the phase-C
//  register layout: lane (c,q) of wave wq holds mix[64wq+ntl*16+c][le=q*16+t].
//  C: per-q-group segmented register accumulation + atomic flush (v5).
// ---------------------------------------------------------------------------
__global__ __launch_bounds__(256, 4) void k_edge(
    const float* __restrict__ vecs,
    const int*   __restrict__ snd_idx, const int* __restrict__ rcv_idx,
    const int*   __restrict__ perm,
    const float* __restrict__ W0, const float* __restrict__ W1,
    const float* __restrict__ W2,
    const float* __restrict__ s_up, const float* __restrict__ v_up,
    float* __restrict__ agg_s, float* __restrict__ agg_v)
{
    __shared__ float h1v[64*69];   // [le][i], stride 69
    __shared__ float h2v[64*69];

    const int tid  = threadIdx.x;
    const int lane = tid & 63;
    const int wq   = __builtin_amdgcn_readfirstlane(tid >> 6);
    const int e0   = blockIdx.x * 64;
    const int c    = lane & 15, q = lane >> 4;

    // --- per-lane metadata for sorted slot e0+lane (all 64 edges) ---
    const int pe_l  = perm[e0 + lane];
    const int rcv_l = rcv_idx[pe_l];
    const int snd_l = snd_idx[pe_l];
    const float vx_l = vecs[pe_l*3+0], vy_l = vecs[pe_l*3+1], vz_l = vecs[pe_l*3+2];
    const float x_l  = sqrtf(vx_l*vx_l + vy_l*vy_l + vz_l*vz_l);
    const float sx_l = (x_l == 0.f) ? 1.f : x_l;
    const float ys_l = SQRT3_F / sx_l;
    const float Y0_l = vx_l * ys_l, Y1_l = vy_l * ys_l, Y2_l = vz_l * ys_l;
    const float msk_l = (x_l == 0.f) ? 0.f : 1.f;

    // ---- A1: bessel + layer0 -> h1v[le][lane], le = wq*16 + t ----
    #pragma unroll 4
    for (int t = 0; t < 16; ++t) {
        const int le = wq*16 + t;
        const float x = __shfl(x_l, le);
        const float sx = (x == 0.f) ? 1.f : x;
        float s1, c1;
        __sincosf(PI_F * x, &s1, &c1);
        const float u  = fminf(x, 1.f);
        const float u2 = u*u, u3 = u2*u;
        const float u6 = u3*u3, u7 = u6*u, u8 = u6*u2;
        const float env  = (x < 1.f) ? (1.f - 28.f*u6 + 48.f*u7 - 21.f*u8) : 0.f;
        const float pref = SQRT2_F * env / sx;
        float h1 = 0.f;
        float sn = s1, snm1 = 0.f;
        const float twoc = 2.f * c1;
        #pragma unroll
        for (int b = 0; b < 8; ++b) {
            h1 = fmaf(pref * sn, W0[b*64 + lane], h1);
            const float snext = fmaf(twoc, sn, -snm1);
            snm1 = sn; sn = snext;
        }
        h1v[le*69 + lane] = swish_f(h1);
    }
    // no barrier: A2 reads only this wave's own rows (compiler waits lgkmcnt)

    // ---- A2: h2 = swish(h1 @ W1), own rows, lane = output channel ----
    {
        float acc2[16];
        #pragma unroll
        for (int t = 0; t < 16; ++t) acc2[t] = 0.f;
        for (int i = 0; i < 64; ++i) {
            const float w = W1[i*64 + lane];           // coalesced, L1-hot
            #pragma unroll
            for (int t = 0; t < 16; ++t)
                acc2[t] = fmaf(h1v[(wq*16 + t)*69 + i], w, acc2[t]);
        }
        #pragma unroll
        for (int t = 0; t < 16; ++t)
            h2v[(wq*16 + t)*69 + lane] = swish_f(acc2[t]);
    }
    __syncthreads();

    // ---- B: mixr[t][ntl] = mix[64wq + ntl*16 + c][le = q*16 + t] ----
    float mixr[16][4];
    #pragma unroll
    for (int t = 0; t < 16; ++t)
        #pragma unroll
        for (int j = 0; j < 4; ++j) mixr[t][j] = 0.f;
    {
        const float* W2c = W2 + 64*wq + c;
        for (int i = 0; i < 64; ++i) {
            const float w0 = W2c[i*256 +  0];
            const float w1 = W2c[i*256 + 16];
            const float w2 = W2c[i*256 + 32];
            const float w3 = W2c[i*256 + 48];
            #pragma unroll
            for (int t = 0; t < 16; ++t) {
                const float h = h2v[(q*16 + t)*69 + i];
                mixr[t][0] = fmaf(h, w0, mixr[t][0]);
                mixr[t][1] = fmaf(h, w1, mixr[t][1]);
                mixr[t][2] = fmaf(h, w2, mixr[t][2]);
                mixr[t][3] = fmaf(h, w3, mixr[t][3]);
            }
        }
    }

    // ---- C: per-q-group segmented scatter-add from registers (v5) ----
    int cur = -1;
    if (wq == 0) {            // agg_s[:, ntl*16+c] += msv * mix0
        float ra0=0.f, ra1=0.f, ra2=0.f, ra3=0.f;
        #pragma unroll
        for (int t = 0; t < 16; ++t) {
            const int sl  = (lane & 48) + t;
            const int rcv = __shfl(rcv_l, sl);
            const int snd = __shfl(snd_l, sl);
            const float msk = __shfl(msk_l, sl);
            if (rcv != cur) {
                if (cur >= 0) {
                    float* p = agg_s + cur*128 + c;
                    unsafeAtomicAdd(p,      ra0);
                    unsafeAtomicAdd(p + 16, ra1);
                    unsafeAtomicAdd(p + 32, ra2);
                    unsafeAtomicAdd(p + 48, ra3);
                }
                ra0 = ra1 = ra2 = ra3 = 0.f; cur = rcv;
            }
            const float* sp = s_up + snd*64 + c;
            ra0 = fmaf(sp[0],  mixr[t][0] * msk, ra0);
            ra1 = fmaf(sp[16], mixr[t][1] * msk, ra1);
            ra2 = fmaf(sp[32], mixr[t][2] * msk, ra2);
            ra3 = fmaf(sp[48], mixr[t][3] * msk, ra3);
        }
        float* p = agg_s + cur*128 + c;
        unsafeAtomicAdd(p,      ra0);
        unsafeAtomicAdd(p + 16, ra1);
        unsafeAtomicAdd(p + 32, ra2);
        unsafeAtomicAdd(p + 48, ra3);
    } else if (wq == 1) {     // agg_s[:, 64+ntl*16+c] += (mv.Y)/sqrt3 * mix1
        float ra0=0.f, ra1=0.f, ra2=0.f, ra3=0.f;
        #pragma unroll
        for (int t = 0; t < 16; ++t) {
            const int sl  = (lane & 48) + t;
            const int rcv = __shfl(rcv_l, sl);
            const int snd = __shfl(snd_l, sl);
            const float msk = __shfl(msk_l, sl);
            const float Y0 = __shfl(Y0_l, sl), Y1 = __shfl(Y1_l, sl), Y2 = __shfl(Y2_l, sl);
            if (rcv != cur) {
                if (cur >= 0) {
                    float* p = agg_s + cur*128 + 64 + c;
                    unsafeAtomicAdd(p,      ra0);
                    unsafeAtomicAdd(p + 16, ra1);
                    unsafeAtomicAdd(p + 32, ra2);
                    unsafeAtomicAdd(p + 48, ra3);
                }
                ra0 = ra1 = ra2 = ra3 = 0.f; cur = rcv;
            }
            const float* vp = v_up + (snd*64 + c)*3;
            const float t00 = (vp[  0]*Y0 + vp[  1]*Y1 + vp[  2]*Y2) * INV_SQRT3_F;
            const float t01 = (vp[ 48]*Y0 + vp[ 49]*Y1 + vp[ 50]*Y2) * INV_SQRT3_F;
            const float t02 = (vp[ 96]*Y0 + vp[ 97]*Y1 + vp[ 98]*Y2) * INV_SQRT3_F;
            const float t03 = (vp[144]*Y0 + vp[145]*Y1 + vp[146]*Y2) * INV_SQRT3_F;
            ra0 = fmaf(t00, mixr[t][0] * msk, ra0);
            ra1 = fmaf(t01, mixr[t][1] * msk, ra1);
            ra2 = fmaf(t02, mixr[t][2] * msk, ra2);
            ra3 = fmaf(t03, mixr[t][3] * msk, ra3);
        }
        float* p = agg_s + cur*128 + 64 + c;
        unsafeAtomicAdd(p,      ra0);
        unsafeAtomicAdd(p + 16, ra1);
        unsafeAtomicAdd(p + 32, ra2);
        unsafeAtomicAdd(p + 48, ra3);
    } else if (wq == 2) {     // agg_v[:, ntl*16+c, m] += mv_m * mix2
        float rv[4][3];
        #pragma unroll
        for (int i = 0; i < 4; ++i) { rv[i][0]=0.f; rv[i][1]=0.f; rv[i][2]=0.f; }
        #pragma unroll
        for (int t = 0; t < 16; ++t) {
            const int sl  = (lane & 48) + t;
            const int rcv = __shfl(rcv_l, sl);
            const int snd = __shfl(snd_l, sl);
            const float msk = __shfl(msk_l, sl);
            if (rcv != cur) {
                if (cur >= 0) {
                    float* p = agg_v + cur*384 + c*3;
                    #pragma unroll
                    for (int ntl = 0; ntl < 4; ++ntl)
                        #pragma unroll
                        for (int m = 0; m < 3; ++m)
                            unsafeAtomicAdd(p + ntl*48 + m, rv[ntl][m]);
                }
                #pragma unroll
                for (int i = 0; i < 4; ++i) { rv[i][0]=0.f; rv[i][1]=0.f; rv[i][2]=0.f; }
                cur = rcv;
            }
            const float* vp = v_up + (snd*64 + c)*3;
            #pragma unroll
            for (int ntl = 0; ntl < 4; ++ntl) {
                const float mx = mixr[t][ntl] * msk;
                #pragma unroll
                for (int m = 0; m < 3; ++m)
                    rv[ntl][m] = fmaf(vp[ntl*48 + m], mx, rv[ntl][m]);
            }
        }
        float* p = agg_v + cur*384 + c*3;
        #pragma unroll
        for (int ntl = 0; ntl < 4; ++ntl)
            #pragma unroll
            for (int m = 0; m < 3; ++m)
                unsafeAtomicAdd(p + ntl*48 + m, rv[ntl][m]);
    } else {                  // agg_v[:, 64+ntl*16+c, m] += msv * Y_m * mix3
        float rv[4][3];
        #pragma unroll
        for (int i = 0; i < 4; ++i) { rv[i][0]=0.f; rv[i][1]=0.f; rv[i][2]=0.f; }
        #pragma unroll
        for (int t = 0; t < 16; ++t) {
            const int sl  = (lane & 48) + t;
            const int rcv = __shfl(rcv_l, sl);
            const int snd = __shfl(snd_l, sl);
            const float msk = __shfl(msk_l, sl);
            const float Y0 = __shfl(Y0_l, sl), Y1 = __shfl(Y1_l, sl), Y2 = __shfl(Y2_l, sl);
            if (rcv != cur) {
                if (cur >= 0) {
                    float* p = agg_v + cur*384 + 192 + c*3;
                    #pragma unroll
                    for (int ntl = 0; ntl < 4; ++ntl)
                        #pragma unroll
                        for (int m = 0; m < 3; ++m)
                            unsafeAtomicAdd(p + ntl*48 + m, rv[ntl][m]);
                }
                #pragma unroll
                for (int i = 0; i < 4; ++i) { rv[i][0]=0.f; rv[i][1]=0.f; rv[i][2]=0.f; }
                cur = rcv;
            }
            const float* sp = s_up + snd*64 + c;
            #pragma unroll
            for (int ntl = 0; ntl < 4; ++ntl) {
                const float mm = sp[ntl*16] * (mixr[t][ntl] * msk);
                rv[ntl][0] = fmaf(mm, Y0, rv[ntl][0]);
                rv[ntl][1] = fmaf(mm, Y1, rv[ntl][1]);
                rv[ntl][2] = fmaf(mm, Y2, rv[ntl][2]);
            }
        }
        float* p = agg_v + cur*384 + 192 + c*3;
        #pragma unroll
        for (int ntl = 0; ntl < 4; ++ntl)
            #pragma unroll
            for (int m = 0; m < 3; ++m)
                unsafeAtomicAdd(p + ntl*48 + m, rv[ntl][m]);
    }
}

// ---------------------------------------------------------------------------
// K3: node down-projection + specie skip + swish gating (round-2, known good).
// ---------------------------------------------------------------------------
__global__ __launch_bounds__(256) void k_node_down(
    const float* __restrict__ ns, const float* __restrict__ nv,
    const int*   __restrict__ spec_idx,
    const float* __restrict__ Wds, const float* __restrict__ Wdv,
    const float* __restrict__ Wsks, const float* __restrict__ Wskv,
    const float* __restrict__ agg_s, const float* __restrict__ agg_v,
    float* __restrict__ out)
{
    const int lane = threadIdx.x & 63;
    const int wq   = __builtin_amdgcn_readfirstlane(threadIdx.x >> 6);
    const int n    = blockIdx.x * 4 + wq;
    const int spec = __builtin_amdgcn_readfirstlane(spec_idx[n]);

    const float* ar  = agg_s + n*128;
    const float* avr = agg_v + n*384;
    float s0 = 0.f, s1 = 0.f, v0 = 0.f, v1 = 0.f, v2 = 0.f;
    for (int i = 0; i < 128; ++i) {
        const float a = ar[i] * INV_AVG;
        s0 = fmaf(a, Wds[i*128 + lane], s0);
        s1 = fmaf(a, Wds[i*128 + 64 + lane], s1);
        const float wv = Wdv[i*64 + lane];
        v0 = fmaf(avr[i*3+0] * INV_AVG, wv, v0);
        v1 = fmaf(avr[i*3+1] * INV_AVG, wv, v1);
        v2 = fmaf(avr[i*3+2] * INV_AVG, wv, v2);
    }
    const float* nsr = ns + n*64;
    const float* nvr = nv + n*192;
    const float* Ws  = Wsks + spec*8192;   // (64,128)
    const float* Wv  = Wskv + spec*4096;   // (64,64)
    for (int i = 0; i < 64; ++i) {
        const float s = nsr[i];
        s0 = fmaf(s, Ws[i*128 + lane], s0);
        s1 = fmaf(s, Ws[i*128 + 64 + lane], s1);
        const float wv = Wv[i*64 + lane];
        v0 = fmaf(nvr[i*3+0], wv, v0);
        v1 = fmaf(nvr[i*3+1], wv, v1);
        v2 = fmaf(nvr[i*3+2], wv, v2);
    }
    const float scal = swish_f(s0);
    const float gate = swish_f(s1);
    out[n*256 + lane]               = scal;
    out[n*256 + 64 + lane*3 + 0]    = v0 * gate;
    out[n*256 + 64 + lane*3 + 1]    = v1 * gate;
    out[n*256 + 64 + lane*3 + 2]    = v2 * gate;
}

// ---------------------------------------------------------------------------
extern "C" void kernel_launch(void* const* d_in, const int* in_sizes, int n_in,
                              void* d_out, int out_size, void* d_ws, size_t ws_size,
                              hipStream_t stream)
{
    (void)in_sizes; (void)n_in; (void)out_size; (void)ws_size;

    const float* vectors      = (const float*)d_in[0];
    const float* node_scalars = (const float*)d_in[1];
    const float* node_vectors = (const float*)d_in[2];
    const int*   node_specie  = (const int*)d_in[3];
    const int*   senders      = (const int*)d_in[4];
    const int*   receivers    = (const int*)d_in[5];
    const float* W_skip_s     = (const float*)d_in[6];
    const float* W_skip_v     = (const float*)d_in[7];
    const float* W_up_s       = (const float*)d_in[8];
    const float* W_up_v       = (const float*)d_in[9];
    const float* W_mlp0       = (const float*)d_in[10];
    const float* W_mlp1       = (const float*)d_in[11];
    const float* W_mlp2       = (const float*)d_in[12];
    const float* W_down_s     = (const float*)d_in[13];
    const float* W_down_v     = (const float*)d_in[14];
    float* out = (float*)d_out;

    // workspace layout (round-2): 15,360,000 f32 + perm 320k ints.
    float* ws    = (float*)d_ws;
    float* s_up  = ws;                        // N*64   = 1,280,000 f32
    float* v_up  = s_up + 1280000;            // N*192  = 3,840,000
    float* agg_s = v_up + 3840000;            // N*128  = 2,560,000
    float* agg_v = agg_s + 2560000;           // N*384  = 7,680,000
    int*   perm  = (int*)(agg_v + 7680000);   // E ints = 320,000
    int*   cnt    = (int*)agg_s;              // aliased scratch (dead before node_up)
    int*   cursor = cnt + 20000;

    // edge counting sort by receiver
    hipLaunchKernelGGL(k_zero_cnt, dim3(79),   dim3(256),  0, stream, cnt);
    hipLaunchKernelGGL(k_hist,     dim3(1250), dim3(256),  0, stream, receivers, cnt);
    hipLaunchKernelGGL(k_scan,     dim3(1),    dim3(1024), 0, stream, cnt, cursor);
    hipLaunchKernelGGL(k_scatter,  dim3(1250), dim3(256),  0, stream, receivers, cursor, perm);

    hipLaunchKernelGGL(k_node_up, dim3(5000), dim3(256), 0, stream,
        node_scalars, node_vectors, W_up_s, W_up_v, s_up, v_up, agg_s, agg_v);
    hipLaunchKernelGGL(k_edge, dim3(5000), dim3(256), 0, stream,
        vectors, senders, receivers, perm, W_mlp0, W_mlp1, W_mlp2,
        s_up, v_up, agg_s, agg_v);
    hipLaunchKernelGGL(k_node_down, dim3(5000), dim3(256), 0, stream,
        node_scalars, node_vectors, node_specie, W_down_s, W_down_v,
        W_skip_s, W_skip_v, agg_s, agg_v, out);
}